// Round 7
// baseline (2487.876 us; speedup 1.0000x reference)
//
#include <hip/hip_runtime.h>

#define T_SEQ 2048
#define NBATCH 64
#define DIM 128      // SEQ_LEN
#define HID 128      // HIDDEN
#define G4 512       // 4*HID

typedef _Float16 h2v  __attribute__((ext_vector_type(2)));
typedef _Float16 f16x8 __attribute__((ext_vector_type(8)));
typedef float    f32x4 __attribute__((ext_vector_type(4)));

__device__ __forceinline__ unsigned pack2(float lo, float hi) {
    h2v v; v.x = (_Float16)lo; v.y = (_Float16)hi;
    return __builtin_bit_cast(unsigned, v);
}
__device__ __forceinline__ float dot2(unsigned a, unsigned b, float c) {
#if __has_builtin(__builtin_amdgcn_fdot2)
    return __builtin_amdgcn_fdot2(__builtin_bit_cast(h2v, a),
                                  __builtin_bit_cast(h2v, b), c, false);
#else
    h2v av = __builtin_bit_cast(h2v, a), bv = __builtin_bit_cast(h2v, b);
    c = fmaf((float)av.x, (float)bv.x, c);
    return fmaf((float)av.y, (float)bv.y, c);
#endif
}
__device__ __forceinline__ unsigned bcast(unsigned v, int l) {
    return (unsigned)__builtin_amdgcn_readlane((int)v, l);
}
__device__ __forceinline__ float rcp_(float x) { return __builtin_amdgcn_rcpf(x); }
__device__ __forceinline__ float sigmoidf_(float x) {
    return rcp_(1.0f + __expf(-x));
}
__device__ __forceinline__ float tanhf_(float x) {
    float e = __expf(-2.0f * fabsf(x));          // in (0,1], no overflow
    float t = (1.0f - e) * rcp_(1.0f + e);
    return copysignf(t, x);
}
// barrier that drains ONLY lgkm (ds) — vm loads keep flowing across it
__device__ __forceinline__ void barrier_lgkm() {
    asm volatile("s_waitcnt lgkmcnt(0)\n\ts_barrier" ::: "memory");
    __builtin_amdgcn_sched_barrier(0);
}

// swizzled f16-index into a 16-row x 128-col f16 LDS tile (row stride 256B)
__device__ __forceinline__ int hswz(int row, int colf16) {
    int byte = row * 256 + colf16 * 2;
    byte ^= (row & 7) << 4;
    return byte >> 1;
}

// ---- Phase 1: pre-activations in f32, stored in MFMA C-fragment layout:
//      pre[idx = lt*128 + (channel>>2)][batch 0..63][reg = channel&3]
//      channel = 4*unit + gate; actual W_ih column = gate*128 + unit
// grid.x = tc, block = 512 (thread g = channel g)
__global__ __launch_bounds__(512, 2) void pre_gemm32(
    const float* __restrict__ x,      // [B][T][DIM]
    const float* __restrict__ Wih,    // [DIM][G4]
    const float* __restrict__ bias,   // [G4]
    float* __restrict__ pre,          // [tc*128][64][4] f32
    int t0)
{
    __shared__ unsigned xs[NBATCH][64];
    const int lt = blockIdx.x;
    const int t  = t0 + lt;
    const int g  = threadIdx.x;        // channel
    const int lane = g & 63;
    const int col = (g & 3) * HID + (g >> 2);   // gate*128 + unit

    for (int i = g; i < NBATCH * 64; i += 512) {
        int row  = i >> 6;
        int word = i & 63;
        float2 v = *reinterpret_cast<const float2*>(
            x + (size_t)row * (T_SEQ * DIM) + (size_t)t * DIM + word * 2);
        xs[row][word] = pack2(v.x, v.y);
    }

    unsigned wpk[64];
    #pragma unroll
    for (int i = 0; i < 64; ++i)
        wpk[i] = pack2(Wih[(size_t)(2 * i) * G4 + col],
                       Wih[(size_t)(2 * i + 1) * G4 + col]);

    __syncthreads();
    const float bg = bias[col];
    const size_t obase = ((size_t)lt * 128 + (g >> 2)) * 256 + (g & 3);

    for (int b = 0; b < NBATCH; ++b) {
        unsigned xw = xs[b][lane];
        float a0 = bg, a1 = 0.f, a2 = 0.f, a3 = 0.f;
        #pragma unroll
        for (int k = 0; k < 64; k += 4) {
            a0 = dot2(bcast(xw, k + 0), wpk[k + 0], a0);
            a1 = dot2(bcast(xw, k + 1), wpk[k + 1], a1);
            a2 = dot2(bcast(xw, k + 2), wpk[k + 2], a2);
            a3 = dot2(bcast(xw, k + 3), wpk[k + 3], a3);
        }
        pre[obase + (size_t)b * 4] = (a0 + a1) + (a2 + a3);
    }
}

// ---- Phase 2: MFMA scan. grid.x = 4 batch-groups of 16. block = 512 (8 waves).
// D[channel 512][batch 16] per step via mfma_f32_16x16x32_f16:
//   A = Whh^T (static frags), B = h (LDS, f16, swizzled), C init = pre (f32).
// Lane (col=l&15, hi=l>>4), wave w, tile j: owns (batch bg*16+col, unit 4*(4w+j)+hi),
// regs 0..3 = gates i,f,g,o of that (batch,unit).
// state (floats): c[4blk*512*4] | h[4blk*512*4] | facc[4blk*512*8]
__global__ __launch_bounds__(512, 1) void lstm_scan_mfma(
    const float* __restrict__ pre,    // [tc*128][64][4]
    const float* __restrict__ Whh,    // [HID][G4]
    const float* __restrict__ h0,
    const float* __restrict__ c0,
    const float* __restrict__ fcw,    // [2][T*HID]
    const float* __restrict__ fcb,
    float* __restrict__ state,
    float* __restrict__ out,          // [B][2]
    int t0, int tc)
{
    __shared__ _Float16 h_lds[2][16 * 128];   // double-buffered, XOR-swizzled
    __shared__ float red[8][16][2];

    const int tid = threadIdx.x;
    const int w   = tid >> 6;
    const int l   = tid & 63;
    const int col = l & 15;           // batch-local (C/B cols) AND A-row index
    const int hi  = l >> 4;
    const int bg  = blockIdx.x;
    const int batch = bg * 16 + col;

    // ---- static A fragments: A[row=16*mg+(l&15)][k=(l>>4)*8+i], mg = 4w+j
    f16x8 afrag[4][4];
    #pragma unroll
    for (int j = 0; j < 4; ++j) {
        const int ch = 16 * (4 * w + j) + col;            // A-row channel
        const int wcol = (ch & 3) * HID + (ch >> 2);      // W_hh column
        #pragma unroll
        for (int ks = 0; ks < 4; ++ks) {
            f16x8 a;
            #pragma unroll
            for (int i = 0; i < 8; ++i) {
                int k = ks * 32 + hi * 8 + i;
                a[i] = (_Float16)Whh[(size_t)k * G4 + wcol];
            }
            afrag[j][ks] = a;
        }
    }

    float*       stC = state;
    float*       stH = state + 4 * 512 * 4;
    float*       stF = state + 2 * 4 * 512 * 4;
    const int    sbase = bg * 512 + tid;

    float c[4], facc0[4], facc1[4], hv[4];
    #pragma unroll
    for (int j = 0; j < 4; ++j) {
        const int uj = 4 * (4 * w + j) + hi;
        if (t0 == 0) {
            hv[j] = h0[batch * HID + uj];
            c[j]  = c0[batch * HID + uj];
            facc0[j] = 0.f; facc1[j] = 0.f;
        } else {
            c[j]  = stC[sbase * 4 + j];
            hv[j] = stH[sbase * 4 + j];
            facc0[j] = stF[sbase * 8 + 2 * j];
            facc1[j] = stF[sbase * 8 + 2 * j + 1];
        }
        h_lds[0][hswz(col, uj)] = (_Float16)hv[j];
    }

    const float* fcw1 = fcw + (size_t)T_SEQ * HID;

    // prefetch step 0
    f32x4 pcur[4]; float fw0c[4], fw1c[4];
    #pragma unroll
    for (int j = 0; j < 4; ++j) {
        const int uj = 4 * (4 * w + j) + hi;
        pcur[j] = *reinterpret_cast<const f32x4*>(
            pre + ((size_t)(4 * (4 * w + j) + hi)) * 256 + batch * 4);
        fw0c[j] = fcw[(size_t)t0 * HID + uj];
        fw1c[j] = fcw1[(size_t)t0 * HID + uj];
    }

    __syncthreads();   // h_lds ready, state loads drained

    for (int s = 0; s < tc; ++s) {
        const int cur = s & 1;
        const int sn  = (s + 1 < tc) ? s + 1 : tc - 1;

        // prefetch next step's pre + fcw (vm, drains lazily before next use)
        f32x4 pnxt[4]; float fw0n[4], fw1n[4];
        #pragma unroll
        for (int j = 0; j < 4; ++j) {
            const int uj = 4 * (4 * w + j) + hi;
            pnxt[j] = *reinterpret_cast<const f32x4*>(
                pre + ((size_t)sn * 128 + 4 * (4 * w + j) + hi) * 256 + batch * 4);
            fw0n[j] = fcw[(size_t)(t0 + sn) * HID + uj];
            fw1n[j] = fcw1[(size_t)(t0 + sn) * HID + uj];
        }

        // B fragments: 8 consecutive k of batch 'col', chunk hi, slice ks
        f16x8 bfrag[4];
        #pragma unroll
        for (int ks = 0; ks < 4; ++ks) {
            int byte = col * 256 + ks * 64 + hi * 16;
            byte ^= (col & 7) << 4;
            bfrag[ks] = *reinterpret_cast<const f16x8*>(
                reinterpret_cast<const char*>(&h_lds[cur][0]) + byte);
        }

        #pragma unroll
        for (int j = 0; j < 4; ++j) {
            f32x4 acc = pcur[j];
            #pragma unroll
            for (int ks = 0; ks < 4; ++ks)
                acc = __builtin_amdgcn_mfma_f32_16x16x32_f16(
                    afrag[j][ks], bfrag[ks], acc, 0, 0, 0);

            float gi = sigmoidf_(acc[0]);
            float gf = sigmoidf_(acc[1]);
            float gg = tanhf_(acc[2]);
            float go = sigmoidf_(acc[3]);
            c[j] = fmaf(gf, c[j], gi * gg);
            float hn = go * tanhf_(c[j]);
            hv[j] = hn;
            facc0[j] = fmaf(hn, fw0c[j], facc0[j]);
            facc1[j] = fmaf(hn, fw1c[j], facc1[j]);
            const int uj = 4 * (4 * w + j) + hi;
            h_lds[cur ^ 1][hswz(col, uj)] = (_Float16)hn;
        }

        #pragma unroll
        for (int j = 0; j < 4; ++j) {
            pcur[j] = pnxt[j]; fw0c[j] = fw0n[j]; fw1c[j] = fw1n[j];
        }
        barrier_lgkm();
    }

    if (t0 + tc >= T_SEQ) {
        float s0 = (facc0[0] + facc0[1]) + (facc0[2] + facc0[3]);
        float s1 = (facc1[0] + facc1[1]) + (facc1[2] + facc1[3]);
        s0 += __shfl_xor(s0, 16); s0 += __shfl_xor(s0, 32);
        s1 += __shfl_xor(s1, 16); s1 += __shfl_xor(s1, 32);
        if (hi == 0) { red[w][col][0] = s0; red[w][col][1] = s1; }
        __syncthreads();
        if (tid < 32) {
            int b = tid >> 1, o = tid & 1;
            float v = 0.f;
            #pragma unroll
            for (int ww = 0; ww < 8; ++ww) v += red[ww][b][o];
            out[(bg * 16 + b) * 2 + o] = v + fcb[o];
        }
    } else {
        #pragma unroll
        for (int j = 0; j < 4; ++j) {
            stC[sbase * 4 + j] = c[j];
            stH[sbase * 4 + j] = hv[j];
            stF[sbase * 8 + 2 * j]     = facc0[j];
            stF[sbase * 8 + 2 * j + 1] = facc1[j];
        }
    }
}

extern "C" void kernel_launch(void* const* d_in, const int* in_sizes, int n_in,
                              void* d_out, int out_size, void* d_ws, size_t ws_size,
                              hipStream_t stream) {
    const float* x    = (const float*)d_in[0];
    const float* h0   = (const float*)d_in[1];
    const float* c0   = (const float*)d_in[2];
    const float* Wih  = (const float*)d_in[3];
    const float* Whh  = (const float*)d_in[4];
    const float* bias = (const float*)d_in[5];
    const float* fcw  = (const float*)d_in[6];
    const float* fcb  = (const float*)d_in[7];
    float* out = (float*)d_out;

    // ws layout: state header (32768 floats = 128 KB), then f32 pre chunk buffer
    float* state = (float*)d_ws;
    const size_t state_floats = (size_t)4 * 512 * 16;   // 32768
    float* pre = state + state_floats;

    const size_t per_t_bytes = (size_t)128 * 64 * 4 * sizeof(float); // 128 KB per step
    size_t avail = (ws_size > state_floats * sizeof(float))
                       ? ws_size - state_floats * sizeof(float) : 0;
    int Tc = (int)(avail / per_t_bytes);
    if (Tc < 1) Tc = 1;
    if (Tc > T_SEQ) Tc = T_SEQ;

    for (int t0 = 0; t0 < T_SEQ; t0 += Tc) {
        int tc = (t0 + Tc <= T_SEQ) ? Tc : (T_SEQ - t0);
        pre_gemm32<<<tc, 512, 0, stream>>>(x, Wih, bias, pre, t0);
        lstm_scan_mfma<<<4, 512, 0, stream>>>(pre, Whh, h0, c0, fcw, fcb,
                                              state, out, t0, tc);
    }
}

// Round 8
// 2280.689 us; speedup vs baseline: 1.0908x; 1.0908x over previous
//
#include <hip/hip_runtime.h>

#define T_SEQ 2048
#define NBATCH 64
#define DIM 128      // SEQ_LEN
#define HID 128      // HIDDEN
#define G4 512       // 4*HID
#define LOG2E 1.44269504088896f

typedef _Float16 h2v   __attribute__((ext_vector_type(2)));
typedef _Float16 f16x8 __attribute__((ext_vector_type(8)));
typedef float    f32x4 __attribute__((ext_vector_type(4)));
typedef float    f32x2 __attribute__((ext_vector_type(2)));

__device__ __forceinline__ float rcp_(float x)  { return __builtin_amdgcn_rcpf(x); }
__device__ __forceinline__ float exp2_(float x) { return __builtin_amdgcn_exp2f(x); }
// sigmoid with input pre-scaled by log2e
__device__ __forceinline__ float sig2_(float a) { return rcp_(1.0f + exp2_(-a)); }
// tanh with input pre-scaled by 2*log2e: tanh(y) = 1 - 2/(1+2^a)
__device__ __forceinline__ float tanh2_(float a) {
    return fmaf(-2.0f, rcp_(1.0f + exp2_(a)), 1.0f);
}
// barrier draining ONLY lgkm (ds) — vm loads keep flowing across it
__device__ __forceinline__ void barrier_lgkm() {
    asm volatile("s_waitcnt lgkmcnt(0)\n\ts_barrier" ::: "memory");
    __builtin_amdgcn_sched_barrier(0);
}

// ---- prep: x f32 -> f16 (same layout); pack fcw into pairs; scaled bias ----
__global__ __launch_bounds__(256) void prep(
    const float* __restrict__ x,      // [B][T][DIM] f32
    const float* __restrict__ fcw,    // [2][T*HID]
    const float* __restrict__ bias,   // [G4] gate-major
    _Float16* __restrict__ x16,       // [B][T][DIM] f16
    float* __restrict__ fc2,          // [T*HID][2]
    float* __restrict__ bias_s)       // [512] unit-major channels, log2e-scaled
{
    const size_t gtid   = (size_t)blockIdx.x * blockDim.x + threadIdx.x;
    const size_t stride = (size_t)gridDim.x * blockDim.x;

    const size_t n_x2 = (size_t)NBATCH * T_SEQ * DIM / 2;
    for (size_t i = gtid; i < n_x2; i += stride) {
        float2 v = reinterpret_cast<const float2*>(x)[i];
        h2v p; p.x = (_Float16)v.x; p.y = (_Float16)v.y;
        reinterpret_cast<h2v*>(x16)[i] = p;
    }
    const size_t n_f = (size_t)T_SEQ * HID;
    for (size_t i = gtid; i < n_f; i += stride) {
        fc2[2 * i]     = fcw[i];
        fc2[2 * i + 1] = fcw[n_f + i];
    }
    for (size_t i = gtid; i < 512; i += stride) {
        int gate = (int)i & 3, u = (int)i >> 2;
        float sc = (gate == 2) ? 2.0f * LOG2E : LOG2E;
        bias_s[i] = bias[gate * HID + u] * sc;
    }
}

// ---- fused scan: 4 blocks x 512 threads (16 batches/block, 8 waves).
// Per step: D[ch 512][batch 16] = bias + Wih~.x_t (16 MFMA) + Whh~.h (16 MFMA),
// channel = 4*unit+gate, C-layout verified in R7: lane(col=l&15,hi=l>>4), wave w,
// tile j -> (batch bg*16+col, unit 16w+4j+hi), regs 0..3 = gates i,f,g,o.
// Weights pre-scaled by log2e (2log2e for g) so activations use raw v_exp_f32.
// h exchanged via LDS stored in B-FRAGMENT layout: frag[buf][ks][lane=hi*16+col][8].
__global__ __launch_bounds__(512, 1) void lstm_fused(
    const _Float16* __restrict__ x16, // [B][T][DIM] f16
    const float* __restrict__ Wih,    // [DIM][G4]
    const float* __restrict__ Whh,    // [HID][G4]
    const float* __restrict__ h0,
    const float* __restrict__ c0,
    const float* __restrict__ fc2,    // [T*HID][2]
    const float* __restrict__ fcb,
    const float* __restrict__ bias_s, // [512] scaled
    float* __restrict__ out)          // [B][2]
{
    __shared__ _Float16 frag[2][4][64][8];   // 8 KB, double-buffered h fragments
    __shared__ float red[8][16][2];

    const int tid = threadIdx.x;
    const int w   = tid >> 6;
    const int l   = tid & 63;
    const int col = l & 15;
    const int hi  = l >> 4;
    const int bg  = blockIdx.x;
    const int batch = bg * 16 + col;

    // ---- static A fragments for both GEMMs, log2e-scaled f16
    f16x8 aX[4][4], aH[4][4];
    #pragma unroll
    for (int j = 0; j < 4; ++j) {
        const int chr  = 16 * (4 * w + j) + col;          // A-row channel
        const int wcol = (chr & 3) * HID + (chr >> 2);    // weight column
        const float sc = ((chr & 3) == 2) ? 2.0f * LOG2E : LOG2E;
        #pragma unroll
        for (int ks = 0; ks < 4; ++ks) {
            f16x8 ax, ah;
            #pragma unroll
            for (int i = 0; i < 8; ++i) {
                int k = ks * 32 + hi * 8 + i;
                ax[i] = (_Float16)(Wih[(size_t)k * G4 + wcol] * sc);
                ah[i] = (_Float16)(Whh[(size_t)k * G4 + wcol] * sc);
            }
            aX[j][ks] = ax; aH[j][ks] = ah;
        }
    }

    // scaled bias as accumulator init (channels 16*(4w+j)+4hi+0..3 consecutive)
    f32x4 bv[4];
    #pragma unroll
    for (int j = 0; j < 4; ++j)
        bv[j] = *reinterpret_cast<const f32x4*>(bias_s + 16 * (4 * w + j) + 4 * hi);

    // state: this lane's 4 units
    int   u[4];
    float c[4], hv[4], f0[4], f1[4];
    #pragma unroll
    for (int j = 0; j < 4; ++j) {
        u[j]  = 16 * w + 4 * j + hi;
        c[j]  = c0[batch * HID + u[j]];
        hv[j] = h0[batch * HID + u[j]];
        f0[j] = 0.f; f1[j] = 0.f;
        // initial h into frag[0]: target (ks_t = w>>1, hi_t = (2w + (j>>1))&3, i_t = 4(j&1)+hi)
        frag[0][w >> 1][(((2 * w + (j >> 1)) & 3) * 16) + col][4 * (j & 1) + hi] =
            (_Float16)hv[j];
    }

    // prefetch t=0 inputs
    const _Float16* xb_base = x16 + (size_t)batch * T_SEQ * DIM + hi * 8;
    f16x8 xb_n[4];
    #pragma unroll
    for (int ks = 0; ks < 4; ++ks)
        xb_n[ks] = *reinterpret_cast<const f16x8*>(xb_base + ks * 32);
    f32x2 fc_n[4];
    #pragma unroll
    for (int j = 0; j < 4; ++j)
        fc_n[j] = *reinterpret_cast<const f32x2*>(fc2 + 2 * (size_t)u[j]);

    __syncthreads();

    for (int t = 0; t < T_SEQ; ++t) {
        const int cur = t & 1;

        f16x8 xb[4]; f32x2 fcp[4];
        #pragma unroll
        for (int ks = 0; ks < 4; ++ks) xb[ks] = xb_n[ks];
        #pragma unroll
        for (int j = 0; j < 4; ++j) fcp[j] = fc_n[j];

        // prefetch next step (lazy vm drain — ~1 full step of latency cover)
        const int tn = (t + 1 < T_SEQ) ? t + 1 : t;
        #pragma unroll
        for (int ks = 0; ks < 4; ++ks)
            xb_n[ks] = *reinterpret_cast<const f16x8*>(
                xb_base + (size_t)tn * DIM + ks * 32);
        #pragma unroll
        for (int j = 0; j < 4; ++j)
            fc_n[j] = *reinterpret_cast<const f32x2*>(
                fc2 + 2 * ((size_t)tn * HID + u[j]));

        // h B-fragments: one conflict-free b128 per ks
        f16x8 bh[4];
        #pragma unroll
        for (int ks = 0; ks < 4; ++ks)
            bh[ks] = *reinterpret_cast<const f16x8*>(&frag[cur][ks][l][0]);

        #pragma unroll
        for (int j = 0; j < 4; ++j) {
            f32x4 acc = bv[j];
            #pragma unroll
            for (int ks = 0; ks < 4; ++ks)
                acc = __builtin_amdgcn_mfma_f32_16x16x32_f16(aX[j][ks], xb[ks], acc, 0, 0, 0);
            #pragma unroll
            for (int ks = 0; ks < 4; ++ks)
                acc = __builtin_amdgcn_mfma_f32_16x16x32_f16(aH[j][ks], bh[ks], acc, 0, 0, 0);

            float gi = sig2_(acc[0]);
            float gf = sig2_(acc[1]);
            float gg = tanh2_(acc[2]);         // == tanh(raw g)
            float go = sig2_(acc[3]);
            c[j] = fmaf(gf, c[j], gi * gg);
            float th = tanh2_(2.0f * LOG2E * c[j]);
            float hn = go * th;
            hv[j] = hn;
            f0[j] = fmaf(hn, fcp[j].x, f0[j]);
            f1[j] = fmaf(hn, fcp[j].y, f1[j]);
            frag[cur ^ 1][w >> 1][(((2 * w + (j >> 1)) & 3) * 16) + col]
                [4 * (j & 1) + hi] = (_Float16)hn;
        }
        barrier_lgkm();
    }

    // ---- FC head reduction
    float s0 = (f0[0] + f0[1]) + (f0[2] + f0[3]);
    float s1 = (f1[0] + f1[1]) + (f1[2] + f1[3]);
    s0 += __shfl_xor(s0, 16); s0 += __shfl_xor(s0, 32);
    s1 += __shfl_xor(s1, 16); s1 += __shfl_xor(s1, 32);
    if (hi == 0) { red[w][col][0] = s0; red[w][col][1] = s1; }
    __syncthreads();
    if (tid < 32) {
        int b2 = tid >> 1, o = tid & 1;
        float v = 0.f;
        #pragma unroll
        for (int ww = 0; ww < 8; ++ww) v += red[ww][b2][o];
        out[(bg * 16 + b2) * 2 + o] = v + fcb[o];
    }
}

extern "C" void kernel_launch(void* const* d_in, const int* in_sizes, int n_in,
                              void* d_out, int out_size, void* d_ws, size_t ws_size,
                              hipStream_t stream) {
    const float* x    = (const float*)d_in[0];
    const float* h0   = (const float*)d_in[1];
    const float* c0   = (const float*)d_in[2];
    const float* Wih  = (const float*)d_in[3];
    const float* Whh  = (const float*)d_in[4];
    const float* bias = (const float*)d_in[5];
    const float* fcw  = (const float*)d_in[6];
    const float* fcb  = (const float*)d_in[7];
    float* out = (float*)d_out;

    // ws layout: x16 (32 MB) | fc2 (2 MB) | bias_s (2 KB)
    char* wsb = (char*)d_ws;
    _Float16* x16    = (_Float16*)wsb;
    float*    fc2    = (float*)(wsb + (size_t)NBATCH * T_SEQ * DIM * 2);
    float*    bias_s = (float*)(wsb + (size_t)NBATCH * T_SEQ * DIM * 2
                                     + (size_t)T_SEQ * HID * 2 * 4);

    prep<<<512, 256, 0, stream>>>(x, fcw, bias, x16, fc2, bias_s);
    lstm_fused<<<4, 512, 0, stream>>>(x16, Wih, Whh, h0, c0, fc2, fcb, bias_s, out);
}